// Round 2
// baseline (1052.259 us; speedup 1.0000x reference)
//
#include <hip/hip_runtime.h>
#include <hip/hip_fp16.h>
#include <cstdint>
#include <cstddef>

#define NQQ  (144*144)        // 20736
#define SCALE 0.17677669529663687f

// ws layout in HALF elements (fp16). Total = 56,623,104 halves = 108 MiB.
#define QH  0ull
#define KH  14155776ull
#define VH  28311552ull
#define AOH 42467328ull

__device__ inline float4 load_h4(const __half* p) {
    uint2 u = *(const uint2*)p;
    __half2 a = *(__half2*)&u.x, b = *(__half2*)&u.y;
    float2 fa = __half22float2(a), fb = __half22float2(b);
    return make_float4(fa.x, fa.y, fb.x, fb.y);
}
__device__ inline void store_h4(__half* p, float4 v) {
    __half2 a = __floats2half2_rn(v.x, v.y);
    __half2 b = __floats2half2_rn(v.z, v.w);
    uint2 u; u.x = *(unsigned int*)&a; u.y = *(unsigned int*)&b;
    *(uint2*)p = u;
}

// ---------------------------------------------------------------------------
// K1: qkv = x @ w_qkv + b_qkv ; scatter fp16 to ws as q*scale | k | v, [bh][n][d]
// M=36864, K=384, N=1152. 128x128 tile, 8x8 micro, 256 threads.
// ---------------------------------------------------------------------------
__launch_bounds__(256)
__global__ void k_qkv_gemm(const float* __restrict__ X, const float* __restrict__ W,
                           const float* __restrict__ bq, __half* __restrict__ ws16) {
    __shared__ float sA[16][132];
    __shared__ float sB[16][132];
    const int t  = threadIdx.x;
    const int tx = t & 15, ty = t >> 4;
    const int r0 = blockIdx.x * 128;
    const int c0 = blockIdx.y * 128;

    float acc[8][8];
#pragma unroll
    for (int i = 0; i < 8; ++i)
#pragma unroll
        for (int j = 0; j < 8; ++j) acc[i][j] = 0.0f;

    for (int kk = 0; kk < 384; kk += 16) {
#pragma unroll
        for (int i = 0; i < 2; ++i) {
            int id  = t * 2 + i;            // 0..511
            int row = id >> 2;              // 0..127
            int kq  = (id & 3) << 2;        // 0,4,8,12
            float4 a4 = *(const float4*)(X + (size_t)(r0 + row) * 384 + kk + kq);
            sA[kq + 0][row] = a4.x; sA[kq + 1][row] = a4.y;
            sA[kq + 2][row] = a4.z; sA[kq + 3][row] = a4.w;
        }
#pragma unroll
        for (int i = 0; i < 2; ++i) {
            int id = t * 2 + i;
            int kr = id >> 5;               // 0..15
            int cq = (id & 31) << 2;        // 0..124
            *(float4*)&sB[kr][cq] = *(const float4*)(W + (size_t)(kk + kr) * 1152 + c0 + cq);
        }
        __syncthreads();
#pragma unroll
        for (int k = 0; k < 16; ++k) {
            float4 a0 = *(const float4*)&sA[k][ty * 4];
            float4 a1 = *(const float4*)&sA[k][ty * 4 + 64];
            float4 b0 = *(const float4*)&sB[k][tx * 4];
            float4 b1 = *(const float4*)&sB[k][tx * 4 + 64];
            float av[8] = {a0.x, a0.y, a0.z, a0.w, a1.x, a1.y, a1.z, a1.w};
            float bv[8] = {b0.x, b0.y, b0.z, b0.w, b1.x, b1.y, b1.z, b1.w};
#pragma unroll
            for (int i = 0; i < 8; ++i)
#pragma unroll
                for (int j = 0; j < 8; ++j) acc[i][j] += av[i] * bv[j];
        }
        __syncthreads();
    }

#pragma unroll
    for (int jc = 0; jc < 2; ++jc) {
        int cb = c0 + tx * 4 + jc * 64;
        int p  = cb / 384;
        int hh = (cb >> 5) % 12;
        int d0 = cb & 31;
        float4 bias = *(const float4*)(bq + cb);
        size_t base = (p == 0) ? QH : ((p == 1) ? KH : VH);
        float sc = (p == 0) ? SCALE : 1.0f;
#pragma unroll
        for (int ic = 0; ic < 2; ++ic) {
#pragma unroll
            for (int i = 0; i < 4; ++i) {
                int r  = r0 + ty * 4 + ic * 64 + i;
                int bw = r / 144;
                int n  = r - bw * 144;
                float4 v;
                v.x = (acc[ic * 4 + i][jc * 4 + 0] + bias.x) * sc;
                v.y = (acc[ic * 4 + i][jc * 4 + 1] + bias.y) * sc;
                v.z = (acc[ic * 4 + i][jc * 4 + 2] + bias.z) * sc;
                v.w = (acc[ic * 4 + i][jc * 4 + 3] + bias.w) * sc;
                store_h4(ws16 + base + (((size_t)bw * 12 + hh) * 144 + n) * 32 + d0, v);
            }
        }
    }
}

// ---------------------------------------------------------------------------
// K2: fused scores + bias/mask + softmax + PV per (b,h). P lives in LDS (fp16).
// 3 row-chunks of 48. Scores: thread rows {tr+16a,a<3} x cols {ti+16j,j<9}.
// PV: rows {tr+16a}, cols {ti, ti+16}. Writes AO fp16 [b][n][h*32+d].
// LDS: 20736 + 18944 + 6912 + 14208 = 60800 B.
// ---------------------------------------------------------------------------
__launch_bounds__(256)
__global__ void k_attn_fused(const __half* __restrict__ ws16,
                             const float* __restrict__ mask,
                             const float* __restrict__ table,
                             const int* __restrict__ pidx,
                             __half* __restrict__ AO) {
    __shared__ float  sK[144][36];
    __shared__ float  sVT[32][148];
    __shared__ float  sQ[48][36];
    __shared__ __half sP[48][148];
    const int bh = blockIdx.x;
    const int b  = bh / 12;
    const int h  = bh - b * 12;
    const int t  = threadIdx.x;
    const int ti = t & 15, tr = t >> 4;

    const unsigned int* kg = (const unsigned int*)(ws16 + KH + (size_t)bh * 4608);
    const unsigned int* vg = (const unsigned int*)(ws16 + VH + (size_t)bh * 4608);
    for (int i = t; i < 2304; i += 256) {
        unsigned int u = kg[i];
        float2 f = __half22float2(*(__half2*)&u);
        int n = i >> 4, d0 = (i & 15) * 2;
        sK[n][d0] = f.x; sK[n][d0 + 1] = f.y;
    }
    for (int i = t; i < 2304; i += 256) {
        unsigned int u = vg[i];
        float2 f = __half22float2(*(__half2*)&u);
        int n = i >> 4, d0 = (i & 15) * 2;
        sVT[d0][n] = f.x; sVT[d0 + 1][n] = f.y;
    }

    const int s_tile = b >> 5;
    const int i1     = b & 31;
    const float* maskb = mask + (size_t)(b & 7) * NQQ;

    for (int c = 0; c < 3; ++c) {
        const int r0 = c * 48;
        const unsigned int* qg = (const unsigned int*)(ws16 + QH + (size_t)bh * 4608 + (size_t)r0 * 32);
        for (int i = t; i < 768; i += 256) {
            unsigned int u = qg[i];
            float2 f = __half22float2(*(__half2*)&u);
            int n = i >> 4, d0 = (i & 15) * 2;
            sQ[n][d0] = f.x; sQ[n][d0 + 1] = f.y;
        }
        __syncthreads();   // sK/sVT (c==0) + sQ ready; prior chunk's PV done

        float acc[3][9];
#pragma unroll
        for (int a = 0; a < 3; ++a)
#pragma unroll
            for (int j = 0; j < 9; ++j) acc[a][j] = 0.0f;

#pragma unroll
        for (int d4 = 0; d4 < 8; ++d4) {
            float4 q4[3], k4[9];
#pragma unroll
            for (int a = 0; a < 3; ++a) q4[a] = *(const float4*)&sQ[tr + 16 * a][d4 * 4];
#pragma unroll
            for (int j = 0; j < 9; ++j) k4[j] = *(const float4*)&sK[ti + 16 * j][d4 * 4];
#pragma unroll
            for (int a = 0; a < 3; ++a)
#pragma unroll
                for (int j = 0; j < 9; ++j)
                    acc[a][j] += q4[a].x * k4[j].x + q4[a].y * k4[j].y +
                                 q4[a].z * k4[j].z + q4[a].w * k4[j].w;
        }

#pragma unroll
        for (int a = 0; a < 3; ++a) {
            const int ln = tr + 16 * a;
            const int n  = r0 + ln;
            float sv[9];
#pragma unroll
            for (int j = 0; j < 9; ++j) {
                int m   = ti + 16 * j;
                int qi  = n * 144 + m;
                int jj  = qi * 8 + s_tile;
                int jm  = jj % 20736;
                int row = pidx[jm];
                float bias = table[(size_t)row * 384 + i1 * 12 + h];
                sv[j] = acc[a][j] + bias + maskb[qi];
            }
            float rmax = sv[0];
#pragma unroll
            for (int j = 1; j < 9; ++j) rmax = fmaxf(rmax, sv[j]);
            for (int off = 1; off < 16; off <<= 1)
                rmax = fmaxf(rmax, __shfl_xor(rmax, off, 16));
            float rsum = 0.0f;
#pragma unroll
            for (int j = 0; j < 9; ++j) { sv[j] = __expf(sv[j] - rmax); rsum += sv[j]; }
            for (int off = 1; off < 16; off <<= 1)
                rsum += __shfl_xor(rsum, off, 16);
            float inv = 1.0f / rsum;
#pragma unroll
            for (int j = 0; j < 9; ++j)
                sP[ln][ti + 16 * j] = __float2half(sv[j] * inv);
        }
        __syncthreads();   // sP ready

        float o[3][2];
#pragma unroll
        for (int a = 0; a < 3; ++a) { o[a][0] = 0.0f; o[a][1] = 0.0f; }
#pragma unroll
        for (int m4 = 0; m4 < 36; ++m4) {
            float4 va = *(const float4*)&sVT[ti][m4 * 4];
            float4 vb = *(const float4*)&sVT[ti + 16][m4 * 4];
#pragma unroll
            for (int a = 0; a < 3; ++a) {
                const __half2* p2 = (const __half2*)&sP[tr + 16 * a][m4 * 4];
                float2 pa = __half22float2(p2[0]);
                float2 pb = __half22float2(p2[1]);
                o[a][0] += pa.x * va.x + pa.y * va.y + pb.x * va.z + pb.y * va.w;
                o[a][1] += pa.x * vb.x + pa.y * vb.y + pb.x * vb.z + pb.y * vb.w;
            }
        }
#pragma unroll
        for (int a = 0; a < 3; ++a) {
            int n = r0 + tr + 16 * a;
            __half* dst = AO + ((size_t)b * 144 + n) * 384 + h * 32;
            dst[ti]      = __float2half(o[a][0]);
            dst[ti + 16] = __float2half(o[a][1]);
        }
        __syncthreads();   // protect sQ/sP overwrite next chunk
    }
}

// ---------------------------------------------------------------------------
// K3: out = AO @ w_out + b_out. M=36864, K=384, N=384. A is fp16, out fp32.
// ---------------------------------------------------------------------------
__launch_bounds__(256)
__global__ void k_out_gemm(const __half* __restrict__ A16, const float* __restrict__ W,
                           const float* __restrict__ bo, float* __restrict__ out) {
    __shared__ float sA[16][132];
    __shared__ float sB[16][132];
    const int t  = threadIdx.x;
    const int tx = t & 15, ty = t >> 4;
    const int r0 = blockIdx.x * 128;
    const int c0 = blockIdx.y * 128;

    float acc[8][8];
#pragma unroll
    for (int i = 0; i < 8; ++i)
#pragma unroll
        for (int j = 0; j < 8; ++j) acc[i][j] = 0.0f;

    for (int kk = 0; kk < 384; kk += 16) {
#pragma unroll
        for (int i = 0; i < 2; ++i) {
            int id  = t * 2 + i;
            int row = id >> 2;
            int kq  = (id & 3) << 2;
            float4 a4 = load_h4(A16 + (size_t)(r0 + row) * 384 + kk + kq);
            sA[kq + 0][row] = a4.x; sA[kq + 1][row] = a4.y;
            sA[kq + 2][row] = a4.z; sA[kq + 3][row] = a4.w;
        }
#pragma unroll
        for (int i = 0; i < 2; ++i) {
            int id = t * 2 + i;
            int kr = id >> 5;
            int cq = (id & 31) << 2;
            *(float4*)&sB[kr][cq] = *(const float4*)(W + (size_t)(kk + kr) * 384 + c0 + cq);
        }
        __syncthreads();
#pragma unroll
        for (int k = 0; k < 16; ++k) {
            float4 a0 = *(const float4*)&sA[k][ty * 4];
            float4 a1 = *(const float4*)&sA[k][ty * 4 + 64];
            float4 b0 = *(const float4*)&sB[k][tx * 4];
            float4 b1 = *(const float4*)&sB[k][tx * 4 + 64];
            float av[8] = {a0.x, a0.y, a0.z, a0.w, a1.x, a1.y, a1.z, a1.w};
            float bv[8] = {b0.x, b0.y, b0.z, b0.w, b1.x, b1.y, b1.z, b1.w};
#pragma unroll
            for (int i = 0; i < 8; ++i)
#pragma unroll
                for (int j = 0; j < 8; ++j) acc[i][j] += av[i] * bv[j];
        }
        __syncthreads();
    }

#pragma unroll
    for (int jc = 0; jc < 2; ++jc) {
        int cb = c0 + tx * 4 + jc * 64;
        float4 bias = *(const float4*)(bo + cb);
#pragma unroll
        for (int ic = 0; ic < 2; ++ic) {
#pragma unroll
            for (int i = 0; i < 4; ++i) {
                int r = r0 + ty * 4 + ic * 64 + i;
                float4 v;
                v.x = acc[ic * 4 + i][jc * 4 + 0] + bias.x;
                v.y = acc[ic * 4 + i][jc * 4 + 1] + bias.y;
                v.z = acc[ic * 4 + i][jc * 4 + 2] + bias.z;
                v.w = acc[ic * 4 + i][jc * 4 + 3] + bias.w;
                *(float4*)(out + (size_t)r * 384 + cb) = v;
            }
        }
    }
}

// ---------------------------------------------------------------------------
extern "C" void kernel_launch(void* const* d_in, const int* in_sizes, int n_in,
                              void* d_out, int out_size, void* d_ws, size_t ws_size,
                              hipStream_t stream) {
    const float* x      = (const float*)d_in[0];
    const float* mask   = (const float*)d_in[1];
    const float* w_qkv  = (const float*)d_in[2];
    const float* b_qkv  = (const float*)d_in[3];
    const float* w_out  = (const float*)d_in[4];
    const float* b_out  = (const float*)d_in[5];
    const float* table  = (const float*)d_in[6];
    const int*   pidx   = (const int*)d_in[7];
    float* out = (float*)d_out;
    __half* ws16 = (__half*)d_ws;

    hipLaunchKernelGGL(k_qkv_gemm,   dim3(288, 9), dim3(256), 0, stream, x, w_qkv, b_qkv, ws16);
    hipLaunchKernelGGL(k_attn_fused, dim3(3072),   dim3(256), 0, stream, ws16, mask, table, pidx, ws16 + AOH);
    hipLaunchKernelGGL(k_out_gemm,   dim3(288, 3), dim3(256), 0, stream, ws16 + AOH, w_out, b_out, out);
}

// Round 3
// 663.080 us; speedup vs baseline: 1.5869x; 1.5869x over previous
//
#include <hip/hip_runtime.h>
#include <hip/hip_fp16.h>
#include <cstdint>
#include <cstddef>

#define NQQ  (144*144)        // 20736
#define SCALE 0.17677669529663687f

// ws layout in HALF elements. Total 57,212,928 halves = 114.4 MiB.
// X16 (qkv-gemm input) and AO (attn output) share region 0 — X16 is dead
// before k_attn_fused writes AO (strictly ordered on one stream).
#define AOH  0ull
#define X16H 0ull
#define QH   14155776ull
#define KH   28311552ull
#define VH   42467328ull
#define WTH  56623104ull      // 442368 halves (1152x384)
#define WOTH 57065472ull      // 147456 halves (384x384)

typedef _Float16 half8 __attribute__((ext_vector_type(8)));
typedef float    f32x4 __attribute__((ext_vector_type(4)));

// ---------------------------------------------------------------------------
// Convert X fp32 -> fp16 (same layout). 14155776 elements = 13824*256*4.
// ---------------------------------------------------------------------------
__launch_bounds__(256)
__global__ void k_cvt_x(const float* __restrict__ X, _Float16* __restrict__ X16) {
    size_t i = (size_t)blockIdx.x * 256 + threadIdx.x;
    float4 f = *(const float4*)&X[i * 4];
    _Float16 h[4] = {(_Float16)f.x, (_Float16)f.y, (_Float16)f.z, (_Float16)f.w};
    *(ushort4*)&X16[i * 4] = *(ushort4*)h;
}

// ---------------------------------------------------------------------------
// Transpose W[K][Cn] fp32 -> WT[Cn][K] fp16. 64x64 tiles, K,Cn multiples of 64.
// ---------------------------------------------------------------------------
__launch_bounds__(256)
__global__ void k_transpose_w(const float* __restrict__ W, _Float16* __restrict__ WT,
                              int K, int Cn) {
    __shared__ _Float16 sT[64][72];
    const int cb = blockIdx.x * 64, kb = blockIdx.y * 64;
    const int t = threadIdx.x;
#pragma unroll
    for (int i = 0; i < 16; ++i) {
        int id = t + 256 * i;
        int kl = id >> 6, cl = id & 63;
        sT[cl][kl] = (_Float16)W[(size_t)(kb + kl) * Cn + cb + cl];
    }
    __syncthreads();
#pragma unroll
    for (int i = 0; i < 16; ++i) {
        int id = t + 256 * i;
        int cl = id >> 6, kl = id & 63;
        WT[(size_t)(cb + cl) * K + kb + kl] = sT[cl][kl];
    }
}

// ---------------------------------------------------------------------------
// K1: qkv = X16 @ WT^T (+bias, scale q) -> scatter fp16 [bh][n][d].
// MFMA 16x16x32 f16. 128x128 tile, 4 waves in 2x2, each 4x4 of 16x16 tiles.
// ---------------------------------------------------------------------------
__launch_bounds__(256)
__global__ void k_qkv_gemm_mfma(const _Float16* __restrict__ X16,
                                const _Float16* __restrict__ WT,
                                const float* __restrict__ bq,
                                _Float16* __restrict__ ws16) {
    __shared__ _Float16 sA[128][40];
    __shared__ _Float16 sBT[128][40];
    const int t    = threadIdx.x;
    const int lane = t & 63;
    const int w    = t >> 6;
    const int quad = lane >> 4;
    const int l15  = lane & 15;
    const int r0   = blockIdx.x * 128, c0 = blockIdx.y * 128;
    const int wr   = (w >> 1) * 64, wc = (w & 1) * 64;

    f32x4 acc[4][4] = {};

    for (int kk = 0; kk < 384; kk += 32) {
#pragma unroll
        for (int i = 0; i < 2; ++i) {
            int id  = t + 256 * i;            // 0..511
            int row = id >> 2;                // 0..127
            int ko  = (id & 3) * 8;           // 0,8,16,24
            *(uint4*)&sA[row][ko]  = *(const uint4*)&X16[(size_t)(r0 + row) * 384 + kk + ko];
            *(uint4*)&sBT[row][ko] = *(const uint4*)&WT[(size_t)(c0 + row) * 384 + kk + ko];
        }
        __syncthreads();
        half8 a[4], b[4];
#pragma unroll
        for (int i = 0; i < 4; ++i) a[i] = *(const half8*)&sA[wr + 16 * i + l15][quad * 8];
#pragma unroll
        for (int j = 0; j < 4; ++j) b[j] = *(const half8*)&sBT[wc + 16 * j + l15][quad * 8];
#pragma unroll
        for (int i = 0; i < 4; ++i)
#pragma unroll
            for (int j = 0; j < 4; ++j)
                acc[i][j] = __builtin_amdgcn_mfma_f32_16x16x32_f16(a[i], b[j], acc[i][j], 0, 0, 0);
        __syncthreads();
    }

#pragma unroll
    for (int j = 0; j < 4; ++j) {
        int c  = c0 + wc + 16 * j + l15;
        int p  = c / 384;
        int hh = (c >> 5) % 12;
        int d0 = c & 31;
        float bias = bq[c];
        float sc   = (p == 0) ? SCALE : 1.0f;
        size_t base = (p == 0) ? QH : ((p == 1) ? KH : VH);
#pragma unroll
        for (int i = 0; i < 4; ++i) {
#pragma unroll
            for (int reg = 0; reg < 4; ++reg) {
                int r  = r0 + wr + 16 * i + quad * 4 + reg;
                int bw = r / 144;
                int n  = r - bw * 144;
                ws16[base + (((size_t)bw * 12 + hh) * 144 + n) * 32 + d0] =
                    (_Float16)((acc[i][j][reg] + bias) * sc);
            }
        }
    }
}

// ---------------------------------------------------------------------------
// K2: fused scores + bias/mask + softmax + PV per (b,h). Unchanged from R2.
// ---------------------------------------------------------------------------
__launch_bounds__(256)
__global__ void k_attn_fused(const __half* __restrict__ ws16,
                             const float* __restrict__ mask,
                             const float* __restrict__ table,
                             const int* __restrict__ pidx,
                             __half* __restrict__ AO) {
    __shared__ float  sK[144][36];
    __shared__ float  sVT[32][148];
    __shared__ float  sQ[48][36];
    __shared__ __half sP[48][148];
    const int bh = blockIdx.x;
    const int b  = bh / 12;
    const int h  = bh - b * 12;
    const int t  = threadIdx.x;
    const int ti = t & 15, tr = t >> 4;

    const unsigned int* kg = (const unsigned int*)(ws16 + KH + (size_t)bh * 4608);
    const unsigned int* vg = (const unsigned int*)(ws16 + VH + (size_t)bh * 4608);
    for (int i = t; i < 2304; i += 256) {
        unsigned int u = kg[i];
        float2 f = __half22float2(*(__half2*)&u);
        int n = i >> 4, d0 = (i & 15) * 2;
        sK[n][d0] = f.x; sK[n][d0 + 1] = f.y;
    }
    for (int i = t; i < 2304; i += 256) {
        unsigned int u = vg[i];
        float2 f = __half22float2(*(__half2*)&u);
        int n = i >> 4, d0 = (i & 15) * 2;
        sVT[d0][n] = f.x; sVT[d0 + 1][n] = f.y;
    }

    const int s_tile = b >> 5;
    const int i1     = b & 31;
    const float* maskb = mask + (size_t)(b & 7) * NQQ;

    for (int c = 0; c < 3; ++c) {
        const int r0 = c * 48;
        const unsigned int* qg = (const unsigned int*)(ws16 + QH + (size_t)bh * 4608 + (size_t)r0 * 32);
        for (int i = t; i < 768; i += 256) {
            unsigned int u = qg[i];
            float2 f = __half22float2(*(__half2*)&u);
            int n = i >> 4, d0 = (i & 15) * 2;
            sQ[n][d0] = f.x; sQ[n][d0 + 1] = f.y;
        }
        __syncthreads();

        float acc[3][9];
#pragma unroll
        for (int a = 0; a < 3; ++a)
#pragma unroll
            for (int j = 0; j < 9; ++j) acc[a][j] = 0.0f;

#pragma unroll
        for (int d4 = 0; d4 < 8; ++d4) {
            float4 q4[3], k4[9];
#pragma unroll
            for (int a = 0; a < 3; ++a) q4[a] = *(const float4*)&sQ[tr + 16 * a][d4 * 4];
#pragma unroll
            for (int j = 0; j < 9; ++j) k4[j] = *(const float4*)&sK[ti + 16 * j][d4 * 4];
#pragma unroll
            for (int a = 0; a < 3; ++a)
#pragma unroll
                for (int j = 0; j < 9; ++j)
                    acc[a][j] += q4[a].x * k4[j].x + q4[a].y * k4[j].y +
                                 q4[a].z * k4[j].z + q4[a].w * k4[j].w;
        }

#pragma unroll
        for (int a = 0; a < 3; ++a) {
            const int ln = tr + 16 * a;
            const int n  = r0 + ln;
            float sv[9];
#pragma unroll
            for (int j = 0; j < 9; ++j) {
                int m   = ti + 16 * j;
                int qi  = n * 144 + m;
                int jj  = qi * 8 + s_tile;
                int jm  = jj % 20736;
                int row = pidx[jm];
                float bias = table[(size_t)row * 384 + i1 * 12 + h];
                sv[j] = acc[a][j] + bias + maskb[qi];
            }
            float rmax = sv[0];
#pragma unroll
            for (int j = 1; j < 9; ++j) rmax = fmaxf(rmax, sv[j]);
            for (int off = 1; off < 16; off <<= 1)
                rmax = fmaxf(rmax, __shfl_xor(rmax, off, 16));
            float rsum = 0.0f;
#pragma unroll
            for (int j = 0; j < 9; ++j) { sv[j] = __expf(sv[j] - rmax); rsum += sv[j]; }
            for (int off = 1; off < 16; off <<= 1)
                rsum += __shfl_xor(rsum, off, 16);
            float inv = 1.0f / rsum;
#pragma unroll
            for (int j = 0; j < 9; ++j)
                sP[ln][ti + 16 * j] = __float2half(sv[j] * inv);
        }
        __syncthreads();

        float o[3][2];
#pragma unroll
        for (int a = 0; a < 3; ++a) { o[a][0] = 0.0f; o[a][1] = 0.0f; }
#pragma unroll
        for (int m4 = 0; m4 < 36; ++m4) {
            float4 va = *(const float4*)&sVT[ti][m4 * 4];
            float4 vb = *(const float4*)&sVT[ti + 16][m4 * 4];
#pragma unroll
            for (int a = 0; a < 3; ++a) {
                const __half2* p2 = (const __half2*)&sP[tr + 16 * a][m4 * 4];
                float2 pa = __half22float2(p2[0]);
                float2 pb = __half22float2(p2[1]);
                o[a][0] += pa.x * va.x + pa.y * va.y + pb.x * va.z + pb.y * va.w;
                o[a][1] += pa.x * vb.x + pa.y * vb.y + pb.x * vb.z + pb.y * vb.w;
            }
        }
#pragma unroll
        for (int a = 0; a < 3; ++a) {
            int n = r0 + tr + 16 * a;
            __half* dst = AO + ((size_t)b * 144 + n) * 384 + h * 32;
            dst[ti]      = __float2half(o[a][0]);
            dst[ti + 16] = __float2half(o[a][1]);
        }
        __syncthreads();
    }
}

// ---------------------------------------------------------------------------
// K3: out = AO @ WoT^T + b_out. Same MFMA skeleton; fp32 output.
// ---------------------------------------------------------------------------
__launch_bounds__(256)
__global__ void k_out_gemm_mfma(const _Float16* __restrict__ A16,
                                const _Float16* __restrict__ WoT,
                                const float* __restrict__ bo,
                                float* __restrict__ out) {
    __shared__ _Float16 sA[128][40];
    __shared__ _Float16 sBT[128][40];
    const int t    = threadIdx.x;
    const int lane = t & 63;
    const int w    = t >> 6;
    const int quad = lane >> 4;
    const int l15  = lane & 15;
    const int r0   = blockIdx.x * 128, c0 = blockIdx.y * 128;
    const int wr   = (w >> 1) * 64, wc = (w & 1) * 64;

    f32x4 acc[4][4] = {};

    for (int kk = 0; kk < 384; kk += 32) {
#pragma unroll
        for (int i = 0; i < 2; ++i) {
            int id  = t + 256 * i;
            int row = id >> 2;
            int ko  = (id & 3) * 8;
            *(uint4*)&sA[row][ko]  = *(const uint4*)&A16[(size_t)(r0 + row) * 384 + kk + ko];
            *(uint4*)&sBT[row][ko] = *(const uint4*)&WoT[(size_t)(c0 + row) * 384 + kk + ko];
        }
        __syncthreads();
        half8 a[4], b[4];
#pragma unroll
        for (int i = 0; i < 4; ++i) a[i] = *(const half8*)&sA[wr + 16 * i + l15][quad * 8];
#pragma unroll
        for (int j = 0; j < 4; ++j) b[j] = *(const half8*)&sBT[wc + 16 * j + l15][quad * 8];
#pragma unroll
        for (int i = 0; i < 4; ++i)
#pragma unroll
            for (int j = 0; j < 4; ++j)
                acc[i][j] = __builtin_amdgcn_mfma_f32_16x16x32_f16(a[i], b[j], acc[i][j], 0, 0, 0);
        __syncthreads();
    }

#pragma unroll
    for (int j = 0; j < 4; ++j) {
        int c = c0 + wc + 16 * j + l15;
        float bias = bo[c];
#pragma unroll
        for (int i = 0; i < 4; ++i) {
#pragma unroll
            for (int reg = 0; reg < 4; ++reg) {
                int r = r0 + wr + 16 * i + quad * 4 + reg;
                out[(size_t)r * 384 + c] = acc[i][j][reg] + bias;
            }
        }
    }
}

// ---------------------------------------------------------------------------
extern "C" void kernel_launch(void* const* d_in, const int* in_sizes, int n_in,
                              void* d_out, int out_size, void* d_ws, size_t ws_size,
                              hipStream_t stream) {
    const float* x      = (const float*)d_in[0];
    const float* mask   = (const float*)d_in[1];
    const float* w_qkv  = (const float*)d_in[2];
    const float* b_qkv  = (const float*)d_in[3];
    const float* w_out  = (const float*)d_in[4];
    const float* b_out  = (const float*)d_in[5];
    const float* table  = (const float*)d_in[6];
    const int*   pidx   = (const int*)d_in[7];
    float* out = (float*)d_out;
    _Float16* ws16 = (_Float16*)d_ws;

    hipLaunchKernelGGL(k_cvt_x,        dim3(13824),  dim3(256), 0, stream, x, ws16 + X16H);
    hipLaunchKernelGGL(k_transpose_w,  dim3(18, 6),  dim3(256), 0, stream, w_qkv, ws16 + WTH, 384, 1152);
    hipLaunchKernelGGL(k_transpose_w,  dim3(6, 6),   dim3(256), 0, stream, w_out, ws16 + WOTH, 384, 384);
    hipLaunchKernelGGL(k_qkv_gemm_mfma, dim3(288, 9), dim3(256), 0, stream,
                       ws16 + X16H, ws16 + WTH, b_qkv, ws16);
    hipLaunchKernelGGL(k_attn_fused,   dim3(3072),   dim3(256), 0, stream,
                       (const __half*)ws16, mask, table, pidx, (__half*)(ws16 + AOH));
    hipLaunchKernelGGL(k_out_gemm_mfma, dim3(288, 3), dim3(256), 0, stream,
                       ws16 + AOH, ws16 + WOTH, b_out, out);
}

// Round 4
// 370.375 us; speedup vs baseline: 2.8411x; 1.7903x over previous
//
#include <hip/hip_runtime.h>
#include <hip/hip_fp16.h>
#include <cstdint>
#include <cstddef>

#define NQQ  (144*144)        // 20736
#define SCALE 0.17677669529663687f

// ws layout in HALF elements. Total 57,212,928 halves = 114.4 MiB.
// X16 (qkv-gemm input) and AO (attn output) share region 0 — X16 is dead
// before the attention kernel writes AO (strictly ordered on one stream).
#define AOH  0ull
#define X16H 0ull
#define QH   14155776ull
#define KH   28311552ull
#define VH   42467328ull
#define WTH  56623104ull      // 442368 halves (1152x384)
#define WOTH 57065472ull      // 147456 halves (384x384)

typedef _Float16 half8 __attribute__((ext_vector_type(8)));
typedef _Float16 half4v __attribute__((ext_vector_type(4)));
typedef float    f32x4 __attribute__((ext_vector_type(4)));

// ---------------------------------------------------------------------------
// Convert X fp32 -> fp16 (same layout). 14155776 elements = 13824*256*4.
// ---------------------------------------------------------------------------
__launch_bounds__(256)
__global__ void k_cvt_x(const float* __restrict__ X, _Float16* __restrict__ X16) {
    size_t i = (size_t)blockIdx.x * 256 + threadIdx.x;
    float4 f = *(const float4*)&X[i * 4];
    _Float16 h[4] = {(_Float16)f.x, (_Float16)f.y, (_Float16)f.z, (_Float16)f.w};
    *(ushort4*)&X16[i * 4] = *(ushort4*)h;
}

// ---------------------------------------------------------------------------
// Transpose W[K][Cn] fp32 -> WT[Cn][K] fp16. 64x64 tiles.
// ---------------------------------------------------------------------------
__launch_bounds__(256)
__global__ void k_transpose_w(const float* __restrict__ W, _Float16* __restrict__ WT,
                              int K, int Cn) {
    __shared__ _Float16 sT[64][72];
    const int cb = blockIdx.x * 64, kb = blockIdx.y * 64;
    const int t = threadIdx.x;
#pragma unroll
    for (int i = 0; i < 16; ++i) {
        int id = t + 256 * i;
        int kl = id >> 6, cl = id & 63;
        sT[cl][kl] = (_Float16)W[(size_t)(kb + kl) * Cn + cb + cl];
    }
    __syncthreads();
#pragma unroll
    for (int i = 0; i < 16; ++i) {
        int id = t + 256 * i;
        int cl = id >> 6, kl = id & 63;
        WT[(size_t)(cb + cl) * K + kb + kl] = sT[cl][kl];
    }
}

// ---------------------------------------------------------------------------
// K1: qkv = X16 @ WT^T (+bias, scale q) -> scatter fp16 [bh][n][d].
// ---------------------------------------------------------------------------
__launch_bounds__(256)
__global__ void k_qkv_gemm_mfma(const _Float16* __restrict__ X16,
                                const _Float16* __restrict__ WT,
                                const float* __restrict__ bq,
                                _Float16* __restrict__ ws16) {
    __shared__ _Float16 sA[128][40];
    __shared__ _Float16 sBT[128][40];
    const int t    = threadIdx.x;
    const int lane = t & 63;
    const int w    = t >> 6;
    const int quad = lane >> 4;
    const int l15  = lane & 15;
    const int r0   = blockIdx.x * 128, c0 = blockIdx.y * 128;
    const int wr   = (w >> 1) * 64, wc = (w & 1) * 64;

    f32x4 acc[4][4] = {};

    for (int kk = 0; kk < 384; kk += 32) {
#pragma unroll
        for (int i = 0; i < 2; ++i) {
            int id  = t + 256 * i;
            int row = id >> 2;
            int ko  = (id & 3) * 8;
            *(uint4*)&sA[row][ko]  = *(const uint4*)&X16[(size_t)(r0 + row) * 384 + kk + ko];
            *(uint4*)&sBT[row][ko] = *(const uint4*)&WT[(size_t)(c0 + row) * 384 + kk + ko];
        }
        __syncthreads();
        half8 a[4], b[4];
#pragma unroll
        for (int i = 0; i < 4; ++i) a[i] = *(const half8*)&sA[wr + 16 * i + l15][quad * 8];
#pragma unroll
        for (int j = 0; j < 4; ++j) b[j] = *(const half8*)&sBT[wc + 16 * j + l15][quad * 8];
#pragma unroll
        for (int i = 0; i < 4; ++i)
#pragma unroll
            for (int j = 0; j < 4; ++j)
                acc[i][j] = __builtin_amdgcn_mfma_f32_16x16x32_f16(a[i], b[j], acc[i][j], 0, 0, 0);
        __syncthreads();
    }

#pragma unroll
    for (int j = 0; j < 4; ++j) {
        int c  = c0 + wc + 16 * j + l15;
        int p  = c / 384;
        int hh = (c >> 5) % 12;
        int d0 = c & 31;
        float bias = bq[c];
        float sc   = (p == 0) ? SCALE : 1.0f;
        size_t base = (p == 0) ? QH : ((p == 1) ? KH : VH);
#pragma unroll
        for (int i = 0; i < 4; ++i) {
#pragma unroll
            for (int reg = 0; reg < 4; ++reg) {
                int r  = r0 + wr + 16 * i + quad * 4 + reg;
                int bw = r / 144;
                int n  = r - bw * 144;
                ws16[base + (((size_t)bw * 12 + hh) * 144 + n) * 32 + d0] =
                    (_Float16)((acc[i][j][reg] + bias) * sc);
            }
        }
    }
}

// ---------------------------------------------------------------------------
// K2: MFMA attention. One (b,h) per block, 192 threads = 3 waves.
// Wave w owns query rows 48w..48w+47 (row-tiles 3w..3w+2).
// S = Q@K^T via 16x16x32 MFMA (27 tiles/wave, 1 K-step).
// softmax in regs (bias from LDS-precomputed 2592-entry table; mask global).
// PV as O^T = V^T @ P^T, K padded 144->160, 5 K-steps of 16x16x32.
// LDS: sP[144][168] (unions sQ[144][40]+sK[144][40]) + sVT[32][168] + sBias[2592]
//    = 48384 + 10752 + 10368 = 69504 B -> 2 blocks/CU.
// ---------------------------------------------------------------------------
__launch_bounds__(192)
__global__ void k_attn_fused_mfma(const _Float16* __restrict__ ws16,
                                  const float* __restrict__ mask,
                                  const float* __restrict__ table,
                                  const int* __restrict__ pidx,
                                  _Float16* __restrict__ AO) {
    __shared__ __align__(16) char smem[69504];
    _Float16 (*sQ)[40]   = (_Float16(*)[40])(smem);
    _Float16 (*sK)[40]   = (_Float16(*)[40])(smem + 11520);
    _Float16 (*sP)[168]  = (_Float16(*)[168])(smem);
    _Float16 (*sVT)[168] = (_Float16(*)[168])(smem + 48384);
    float*    sBias      = (float*)(smem + 59136);

    const int bh = blockIdx.x;
    const int b  = bh / 12;
    const int h  = bh - b * 12;
    const int t  = threadIdx.x;
    const int w    = t >> 6;
    const int lane = t & 63;
    const int quad = lane >> 4;
    const int l15  = lane & 15;

    const int s_tile = b >> 5;
    const int i1     = b & 31;
    const float* maskb = mask + (size_t)(b & 7) * NQQ;

    // --- phase 1: cooperative loads ---
    const _Float16* qg = ws16 + QH + (size_t)bh * 4608;
    const _Float16* kg = ws16 + KH + (size_t)bh * 4608;
    const _Float16* vg = ws16 + VH + (size_t)bh * 4608;
    for (int i = t; i < 576; i += 192) {          // Q: 144 rows x 4 half8
        int row = i >> 2, ko = (i & 3) * 8;
        *(uint4*)&sQ[row][ko] = *(const uint4*)&qg[row * 32 + ko];
    }
    for (int i = t; i < 576; i += 192) {          // K
        int row = i >> 2, ko = (i & 3) * 8;
        *(uint4*)&sK[row][ko] = *(const uint4*)&kg[row * 32 + ko];
    }
    for (int i = t; i < 2304; i += 192) {         // V -> V^T (half2 granularity)
        unsigned int u = ((const unsigned int*)vg)[i];
        int m = i >> 4, d0 = (i & 15) * 2;
        sVT[d0][m]     = ((const _Float16*)&u)[0];
        sVT[d0 + 1][m] = ((const _Float16*)&u)[1];
    }
    for (int i = t; i < 512; i += 192) {          // V^T zero-pad cols 144..159
        int d = i & 31, m = 144 + (i >> 5);
        sVT[d][m] = (_Float16)0;
    }
    for (int i = t; i < 2592; i += 192) {         // bias precompute
        int row = pidx[8 * i + s_tile];
        sBias[i] = table[(size_t)row * 384 + i1 * 12 + h];
    }
    __syncthreads();

    // --- phase 2: S = Q @ K^T (per wave: 3 row-tiles x 9 col-tiles) ---
    half8 aq[3], bk[9];
#pragma unroll
    for (int a = 0; a < 3; ++a) aq[a] = *(const half8*)&sQ[(3 * w + a) * 16 + l15][quad * 8];
#pragma unroll
    for (int j = 0; j < 9; ++j) bk[j] = *(const half8*)&sK[j * 16 + l15][quad * 8];
    f32x4 s[3][9] = {};
#pragma unroll
    for (int a = 0; a < 3; ++a)
#pragma unroll
        for (int j = 0; j < 9; ++j)
            s[a][j] = __builtin_amdgcn_mfma_f32_16x16x32_f16(aq[a], bk[j], s[a][j], 0, 0, 0);

    __syncthreads();   // all waves done reading sQ/sK; sP may overwrite

    // --- phase 3: bias + mask + softmax ; P -> LDS fp16 ---
#pragma unroll
    for (int a = 0; a < 3; ++a) {
        const int nb = (3 * w + a) * 16 + quad * 4;
        float sv[4][9];
#pragma unroll
        for (int reg = 0; reg < 4; ++reg) {
            int n  = nb + reg;
            int bo = (n % 18) * 144 + l15;
            const float* mrow = maskb + (size_t)n * 144 + l15;
#pragma unroll
            for (int j = 0; j < 9; ++j)
                sv[reg][j] = s[a][j][reg] + sBias[bo + 16 * j] + mrow[16 * j];
        }
#pragma unroll
        for (int reg = 0; reg < 4; ++reg) {
            float rmax = sv[reg][0];
#pragma unroll
            for (int j = 1; j < 9; ++j) rmax = fmaxf(rmax, sv[reg][j]);
            for (int off = 1; off < 16; off <<= 1)
                rmax = fmaxf(rmax, __shfl_xor(rmax, off, 16));
            float rsum = 0.0f;
#pragma unroll
            for (int j = 0; j < 9; ++j) { sv[reg][j] = __expf(sv[reg][j] - rmax); rsum += sv[reg][j]; }
            for (int off = 1; off < 16; off <<= 1)
                rsum += __shfl_xor(rsum, off, 16);
            float inv = 1.0f / rsum;
            int n = nb + reg;
#pragma unroll
            for (int j = 0; j < 9; ++j)
                sP[n][16 * j + l15] = (_Float16)(sv[reg][j] * inv);
        }
    }
    // zero-pad own rows' cols 144..159
    for (int i = lane; i < 768; i += 64)
        sP[48 * w + (i >> 4)][144 + (i & 15)] = (_Float16)0;

    // --- phase 4: O^T = V^T @ P^T (own q-tiles only; no barrier needed) ---
    f32x4 o[2][3] = {};
#pragma unroll
    for (int kt = 0; kt < 5; ++kt) {
        half8 av[2], bp[3];
#pragma unroll
        for (int dt = 0; dt < 2; ++dt) av[dt] = *(const half8*)&sVT[dt * 16 + l15][kt * 32 + quad * 8];
#pragma unroll
        for (int ct = 0; ct < 3; ++ct) bp[ct] = *(const half8*)&sP[(3 * w + ct) * 16 + l15][kt * 32 + quad * 8];
#pragma unroll
        for (int dt = 0; dt < 2; ++dt)
#pragma unroll
            for (int ct = 0; ct < 3; ++ct)
                o[dt][ct] = __builtin_amdgcn_mfma_f32_16x16x32_f16(av[dt], bp[ct], o[dt][ct], 0, 0, 0);
    }

    // --- stores: O^T[d][q] -> AO[b][q][h*32+d], 4 consecutive d per thread ---
#pragma unroll
    for (int dt = 0; dt < 2; ++dt)
#pragma unroll
        for (int ct = 0; ct < 3; ++ct) {
            int q = (3 * w + ct) * 16 + l15;
            int d = dt * 16 + quad * 4;
            half4v hv;
#pragma unroll
            for (int reg = 0; reg < 4; ++reg) hv[reg] = (_Float16)o[dt][ct][reg];
            *(half4v*)&AO[((size_t)b * 144 + q) * 384 + h * 32 + d] = hv;
        }
}

// ---------------------------------------------------------------------------
// K3: out = AO @ WoT^T + b_out. fp32 output.
// ---------------------------------------------------------------------------
__launch_bounds__(256)
__global__ void k_out_gemm_mfma(const _Float16* __restrict__ A16,
                                const _Float16* __restrict__ WoT,
                                const float* __restrict__ bo,
                                float* __restrict__ out) {
    __shared__ _Float16 sA[128][40];
    __shared__ _Float16 sBT[128][40];
    const int t    = threadIdx.x;
    const int lane = t & 63;
    const int w    = t >> 6;
    const int quad = lane >> 4;
    const int l15  = lane & 15;
    const int r0   = blockIdx.x * 128, c0 = blockIdx.y * 128;
    const int wr   = (w >> 1) * 64, wc = (w & 1) * 64;

    f32x4 acc[4][4] = {};

    for (int kk = 0; kk < 384; kk += 32) {
#pragma unroll
        for (int i = 0; i < 2; ++i) {
            int id  = t + 256 * i;
            int row = id >> 2;
            int ko  = (id & 3) * 8;
            *(uint4*)&sA[row][ko]  = *(const uint4*)&A16[(size_t)(r0 + row) * 384 + kk + ko];
            *(uint4*)&sBT[row][ko] = *(const uint4*)&WoT[(size_t)(c0 + row) * 384 + kk + ko];
        }
        __syncthreads();
        half8 a[4], b[4];
#pragma unroll
        for (int i = 0; i < 4; ++i) a[i] = *(const half8*)&sA[wr + 16 * i + l15][quad * 8];
#pragma unroll
        for (int j = 0; j < 4; ++j) b[j] = *(const half8*)&sBT[wc + 16 * j + l15][quad * 8];
#pragma unroll
        for (int i = 0; i < 4; ++i)
#pragma unroll
            for (int j = 0; j < 4; ++j)
                acc[i][j] = __builtin_amdgcn_mfma_f32_16x16x32_f16(a[i], b[j], acc[i][j], 0, 0, 0);
        __syncthreads();
    }

#pragma unroll
    for (int j = 0; j < 4; ++j) {
        int c = c0 + wc + 16 * j + l15;
        float bias = bo[c];
#pragma unroll
        for (int i = 0; i < 4; ++i) {
#pragma unroll
            for (int reg = 0; reg < 4; ++reg) {
                int r = r0 + wr + 16 * i + quad * 4 + reg;
                out[(size_t)r * 384 + c] = acc[i][j][reg] + bias;
            }
        }
    }
}

// ---------------------------------------------------------------------------
extern "C" void kernel_launch(void* const* d_in, const int* in_sizes, int n_in,
                              void* d_out, int out_size, void* d_ws, size_t ws_size,
                              hipStream_t stream) {
    const float* x      = (const float*)d_in[0];
    const float* mask   = (const float*)d_in[1];
    const float* w_qkv  = (const float*)d_in[2];
    const float* b_qkv  = (const float*)d_in[3];
    const float* w_out  = (const float*)d_in[4];
    const float* b_out  = (const float*)d_in[5];
    const float* table  = (const float*)d_in[6];
    const int*   pidx   = (const int*)d_in[7];
    float* out = (float*)d_out;
    _Float16* ws16 = (_Float16*)d_ws;

    hipLaunchKernelGGL(k_cvt_x,         dim3(13824),  dim3(256), 0, stream, x, ws16 + X16H);
    hipLaunchKernelGGL(k_transpose_w,   dim3(18, 6),  dim3(256), 0, stream, w_qkv, ws16 + WTH, 384, 1152);
    hipLaunchKernelGGL(k_transpose_w,   dim3(6, 6),   dim3(256), 0, stream, w_out, ws16 + WOTH, 384, 384);
    hipLaunchKernelGGL(k_qkv_gemm_mfma, dim3(288, 9), dim3(256), 0, stream,
                       ws16 + X16H, ws16 + WTH, b_qkv, ws16);
    hipLaunchKernelGGL(k_attn_fused_mfma, dim3(3072), dim3(192), 0, stream,
                       ws16, mask, table, pidx, ws16 + AOH);
    hipLaunchKernelGGL(k_out_gemm_mfma, dim3(288, 3), dim3(256), 0, stream,
                       ws16 + AOH, ws16 + WOTH, b_out, out);
}

// Round 5
// 344.457 us; speedup vs baseline: 3.0548x; 1.0752x over previous
//
#include <hip/hip_runtime.h>
#include <hip/hip_fp16.h>
#include <cstdint>
#include <cstddef>

#define NQQ  (144*144)        // 20736
#define SCALE 0.17677669529663687f

// ws layout in HALF elements. Total 57,212,928 halves = 114.4 MiB.
// X16 (qkv-gemm input) and AO (attn output) share region 0 — X16 is dead
// before the attention kernel writes AO (strictly ordered on one stream).
#define AOH  0ull
#define X16H 0ull
#define QH   14155776ull
#define KH   28311552ull
#define VH   42467328ull
#define WTH  56623104ull      // 442368 halves (1152x384)
#define WOTH 57065472ull      // 147456 halves (384x384)

typedef _Float16 half8 __attribute__((ext_vector_type(8)));
typedef _Float16 half4v __attribute__((ext_vector_type(4)));
typedef float    f32x4 __attribute__((ext_vector_type(4)));

// ---------------------------------------------------------------------------
// PREP (one dispatch): blocks [0,13824) convert X fp32->fp16;
// [13824,13932) transpose w_qkv; [13932,13968) transpose w_out.
// ---------------------------------------------------------------------------
__launch_bounds__(256)
__global__ void k_prep(const float* __restrict__ X, _Float16* __restrict__ X16,
                       const float* __restrict__ Wq, _Float16* __restrict__ WqT,
                       const float* __restrict__ Wo, _Float16* __restrict__ WoT) {
    const int bid = blockIdx.x;
    const int t   = threadIdx.x;
    if (bid < 13824) {
        size_t i = (size_t)bid * 256 + t;
        float4 f = *(const float4*)&X[i * 4];
        _Float16 h[4] = {(_Float16)f.x, (_Float16)f.y, (_Float16)f.z, (_Float16)f.w};
        *(ushort4*)&X16[i * 4] = *(ushort4*)h;
        return;
    }
    __shared__ _Float16 sT[64][72];
    const float* W; _Float16* WT; int K, Cn, cb, kb;
    if (bid < 13932) {
        int j = bid - 13824;              // 108 tiles: 18 x 6
        W = Wq; WT = WqT; K = 384; Cn = 1152;
        cb = (j % 18) * 64; kb = (j / 18) * 64;
    } else {
        int j = bid - 13932;              // 36 tiles: 6 x 6
        W = Wo; WT = WoT; K = 384; Cn = 384;
        cb = (j % 6) * 64; kb = (j / 6) * 64;
    }
#pragma unroll
    for (int i = 0; i < 16; ++i) {
        int id = t + 256 * i;
        int kl = id >> 6, cl = id & 63;
        sT[cl][kl] = (_Float16)W[(size_t)(kb + kl) * Cn + cb + cl];
    }
    __syncthreads();
#pragma unroll
    for (int i = 0; i < 16; ++i) {
        int id = t + 256 * i;
        int cl = id >> 6, kl = id & 63;
        WT[(size_t)(cb + cl) * K + kb + kl] = sT[cl][kl];
    }
}

// ---------------------------------------------------------------------------
// K1: qkv = X16 @ WT^T (+bias, scale q) -> scatter fp16 [bh][n][d].
// ---------------------------------------------------------------------------
__launch_bounds__(256)
__global__ void k_qkv_gemm_mfma(const _Float16* __restrict__ X16,
                                const _Float16* __restrict__ WT,
                                const float* __restrict__ bq,
                                _Float16* __restrict__ ws16) {
    __shared__ _Float16 sA[128][40];
    __shared__ _Float16 sBT[128][40];
    const int t    = threadIdx.x;
    const int lane = t & 63;
    const int w    = t >> 6;
    const int quad = lane >> 4;
    const int l15  = lane & 15;
    const int r0   = blockIdx.x * 128, c0 = blockIdx.y * 128;
    const int wr   = (w >> 1) * 64, wc = (w & 1) * 64;

    f32x4 acc[4][4] = {};

    for (int kk = 0; kk < 384; kk += 32) {
#pragma unroll
        for (int i = 0; i < 2; ++i) {
            int id  = t + 256 * i;
            int row = id >> 2;
            int ko  = (id & 3) * 8;
            *(uint4*)&sA[row][ko]  = *(const uint4*)&X16[(size_t)(r0 + row) * 384 + kk + ko];
            *(uint4*)&sBT[row][ko] = *(const uint4*)&WT[(size_t)(c0 + row) * 384 + kk + ko];
        }
        __syncthreads();
        half8 a[4], b[4];
#pragma unroll
        for (int i = 0; i < 4; ++i) a[i] = *(const half8*)&sA[wr + 16 * i + l15][quad * 8];
#pragma unroll
        for (int j = 0; j < 4; ++j) b[j] = *(const half8*)&sBT[wc + 16 * j + l15][quad * 8];
#pragma unroll
        for (int i = 0; i < 4; ++i)
#pragma unroll
            for (int j = 0; j < 4; ++j)
                acc[i][j] = __builtin_amdgcn_mfma_f32_16x16x32_f16(a[i], b[j], acc[i][j], 0, 0, 0);
        __syncthreads();
    }

#pragma unroll
    for (int j = 0; j < 4; ++j) {
        int c  = c0 + wc + 16 * j + l15;
        int p  = c / 384;
        int hh = (c >> 5) % 12;
        int d0 = c & 31;
        float bias = bq[c];
        float sc   = (p == 0) ? SCALE : 1.0f;
        size_t base = (p == 0) ? QH : ((p == 1) ? KH : VH);
#pragma unroll
        for (int i = 0; i < 4; ++i) {
#pragma unroll
            for (int reg = 0; reg < 4; ++reg) {
                int r  = r0 + wr + 16 * i + quad * 4 + reg;
                int bw = r / 144;
                int n  = r - bw * 144;
                ws16[base + (((size_t)bw * 12 + hh) * 144 + n) * 32 + d0] =
                    (_Float16)((acc[i][j][reg] + bias) * sc);
            }
        }
    }
}

// ---------------------------------------------------------------------------
// K2: MFMA attention. One (b,h) per block, 576 threads = 9 waves.
// Wave w owns q-tile w (query rows 16w..16w+15).
// S = Q@K^T via 16x16x32 MFMA (9 tiles/wave, 1 K-step);
// softmax (bias from LDS-precomputed table; mask from global);
// PV as O^T = V^T @ P^T, K padded 144->160, 5 K-steps; 10 MFMAs/wave.
// LDS identical to R4 (69504 B, 2 blocks/CU) but 18 waves/CU now.
// ---------------------------------------------------------------------------
__launch_bounds__(576)
__global__ void k_attn_fused_mfma(const _Float16* __restrict__ ws16,
                                  const float* __restrict__ mask,
                                  const float* __restrict__ table,
                                  const int* __restrict__ pidx,
                                  _Float16* __restrict__ AO) {
    __shared__ __align__(16) char smem[69504];
    _Float16 (*sQ)[40]   = (_Float16(*)[40])(smem);
    _Float16 (*sK)[40]   = (_Float16(*)[40])(smem + 11520);
    _Float16 (*sP)[168]  = (_Float16(*)[168])(smem);
    _Float16 (*sVT)[168] = (_Float16(*)[168])(smem + 48384);
    float*    sBias      = (float*)(smem + 59136);

    const int bh = blockIdx.x;
    const int b  = bh / 12;
    const int h  = bh - b * 12;
    const int t  = threadIdx.x;
    const int w    = t >> 6;        // 0..8 : q-tile index
    const int lane = t & 63;
    const int quad = lane >> 4;
    const int l15  = lane & 15;

    const int s_tile = b >> 5;
    const int i1     = b & 31;
    const float* maskb = mask + (size_t)(b & 7) * NQQ;

    // --- phase 1: cooperative loads (576 threads) ---
    const _Float16* qg = ws16 + QH + (size_t)bh * 4608;
    const _Float16* kg = ws16 + KH + (size_t)bh * 4608;
    const _Float16* vg = ws16 + VH + (size_t)bh * 4608;
    if (t < 576) {                                 // Q,K: one uint4 each
        int row = t >> 2, ko = (t & 3) * 8;
        *(uint4*)&sQ[row][ko] = *(const uint4*)&qg[row * 32 + ko];
        *(uint4*)&sK[row][ko] = *(const uint4*)&kg[row * 32 + ko];
    }
    for (int i = t; i < 2304; i += 576) {          // V -> V^T
        unsigned int u = ((const unsigned int*)vg)[i];
        int m = i >> 4, d0 = (i & 15) * 2;
        sVT[d0][m]     = ((const _Float16*)&u)[0];
        sVT[d0 + 1][m] = ((const _Float16*)&u)[1];
    }
    if (t < 512) {                                 // V^T zero-pad cols 144..159
        int d = t & 31, m = 144 + (t >> 5);
        sVT[d][m] = (_Float16)0;
    }
    for (int i = t; i < 2592; i += 576) {          // bias precompute
        int row = pidx[8 * i + s_tile];
        sBias[i] = table[(size_t)row * 384 + i1 * 12 + h];
    }
    __syncthreads();

    // --- phase 2: S-tile = Q-tile @ K^T (9 col-tiles) ---
    half8 aq = *(const half8*)&sQ[16 * w + l15][quad * 8];
    half8 bk[9];
#pragma unroll
    for (int j = 0; j < 9; ++j) bk[j] = *(const half8*)&sK[16 * j + l15][quad * 8];
    f32x4 s[9] = {};
#pragma unroll
    for (int j = 0; j < 9; ++j)
        s[j] = __builtin_amdgcn_mfma_f32_16x16x32_f16(aq, bk[j], s[j], 0, 0, 0);

    __syncthreads();   // all waves done reading sQ/sK; sP may overwrite

    // --- phase 3: bias + mask + softmax ; P -> LDS fp16 (own 16 rows) ---
    {
        const int nb = 16 * w + quad * 4;
        float sv[4][9];
#pragma unroll
        for (int reg = 0; reg < 4; ++reg) {
            int n  = nb + reg;
            int bo = (n % 18) * 144 + l15;
            const float* mrow = maskb + (size_t)n * 144 + l15;
#pragma unroll
            for (int j = 0; j < 9; ++j)
                sv[reg][j] = s[j][reg] + sBias[bo + 16 * j] + mrow[16 * j];
        }
#pragma unroll
        for (int reg = 0; reg < 4; ++reg) {
            float rmax = sv[reg][0];
#pragma unroll
            for (int j = 1; j < 9; ++j) rmax = fmaxf(rmax, sv[reg][j]);
            for (int off = 1; off < 16; off <<= 1)
                rmax = fmaxf(rmax, __shfl_xor(rmax, off, 16));
            float rsum = 0.0f;
#pragma unroll
            for (int j = 0; j < 9; ++j) { sv[reg][j] = __expf(sv[reg][j] - rmax); rsum += sv[reg][j]; }
            for (int off = 1; off < 16; off <<= 1)
                rsum += __shfl_xor(rsum, off, 16);
            float inv = 1.0f / rsum;
            int n = nb + reg;
#pragma unroll
            for (int j = 0; j < 9; ++j)
                sP[n][16 * j + l15] = (_Float16)(sv[reg][j] * inv);
        }
    }
    // zero-pad own rows' cols 144..159
    for (int i = lane; i < 256; i += 64)
        sP[16 * w + (i >> 4)][144 + (i & 15)] = (_Float16)0;

    // --- phase 4: O^T-tile = V^T @ P^T (own q-tile; wave-local, no barrier) ---
    f32x4 o[2] = {};
#pragma unroll
    for (int kt = 0; kt < 5; ++kt) {
        half8 bp = *(const half8*)&sP[16 * w + l15][kt * 32 + quad * 8];
#pragma unroll
        for (int dt = 0; dt < 2; ++dt) {
            half8 av = *(const half8*)&sVT[dt * 16 + l15][kt * 32 + quad * 8];
            o[dt] = __builtin_amdgcn_mfma_f32_16x16x32_f16(av, bp, o[dt], 0, 0, 0);
        }
    }

    // --- stores: O^T[d][q] -> AO[b][q][h*32+d] ---
#pragma unroll
    for (int dt = 0; dt < 2; ++dt) {
        int q = 16 * w + l15;
        int d = dt * 16 + quad * 4;
        half4v hv;
#pragma unroll
        for (int reg = 0; reg < 4; ++reg) hv[reg] = (_Float16)o[dt][reg];
        *(half4v*)&AO[((size_t)b * 144 + q) * 384 + h * 32 + d] = hv;
    }
}

// ---------------------------------------------------------------------------
// K3: out = AO @ WoT^T + b_out. fp32 output.
// ---------------------------------------------------------------------------
__launch_bounds__(256)
__global__ void k_out_gemm_mfma(const _Float16* __restrict__ A16,
                                const _Float16* __restrict__ WoT,
                                const float* __restrict__ bo,
                                float* __restrict__ out) {
    __shared__ _Float16 sA[128][40];
    __shared__ _Float16 sBT[128][40];
    const int t    = threadIdx.x;
    const int lane = t & 63;
    const int w    = t >> 6;
    const int quad = lane >> 4;
    const int l15  = lane & 15;
    const int r0   = blockIdx.x * 128, c0 = blockIdx.y * 128;
    const int wr   = (w >> 1) * 64, wc = (w & 1) * 64;

    f32x4 acc[4][4] = {};

    for (int kk = 0; kk < 384; kk += 32) {
#pragma unroll
        for (int i = 0; i < 2; ++i) {
            int id  = t + 256 * i;
            int row = id >> 2;
            int ko  = (id & 3) * 8;
            *(uint4*)&sA[row][ko]  = *(const uint4*)&A16[(size_t)(r0 + row) * 384 + kk + ko];
            *(uint4*)&sBT[row][ko] = *(const uint4*)&WoT[(size_t)(c0 + row) * 384 + kk + ko];
        }
        __syncthreads();
        half8 a[4], b[4];
#pragma unroll
        for (int i = 0; i < 4; ++i) a[i] = *(const half8*)&sA[wr + 16 * i + l15][quad * 8];
#pragma unroll
        for (int j = 0; j < 4; ++j) b[j] = *(const half8*)&sBT[wc + 16 * j + l15][quad * 8];
#pragma unroll
        for (int i = 0; i < 4; ++i)
#pragma unroll
            for (int j = 0; j < 4; ++j)
                acc[i][j] = __builtin_amdgcn_mfma_f32_16x16x32_f16(a[i], b[j], acc[i][j], 0, 0, 0);
        __syncthreads();
    }

#pragma unroll
    for (int j = 0; j < 4; ++j) {
        int c = c0 + wc + 16 * j + l15;
        float bias = bo[c];
#pragma unroll
        for (int i = 0; i < 4; ++i) {
#pragma unroll
            for (int reg = 0; reg < 4; ++reg) {
                int r = r0 + wr + 16 * i + quad * 4 + reg;
                out[(size_t)r * 384 + c] = acc[i][j][reg] + bias;
            }
        }
    }
}

// ---------------------------------------------------------------------------
extern "C" void kernel_launch(void* const* d_in, const int* in_sizes, int n_in,
                              void* d_out, int out_size, void* d_ws, size_t ws_size,
                              hipStream_t stream) {
    const float* x      = (const float*)d_in[0];
    const float* mask   = (const float*)d_in[1];
    const float* w_qkv  = (const float*)d_in[2];
    const float* b_qkv  = (const float*)d_in[3];
    const float* w_out  = (const float*)d_in[4];
    const float* b_out  = (const float*)d_in[5];
    const float* table  = (const float*)d_in[6];
    const int*   pidx   = (const int*)d_in[7];
    float* out = (float*)d_out;
    _Float16* ws16 = (_Float16*)d_ws;

    hipLaunchKernelGGL(k_prep,          dim3(13968), dim3(256), 0, stream,
                       x, ws16 + X16H, w_qkv, ws16 + WTH, w_out, ws16 + WOTH);
    hipLaunchKernelGGL(k_qkv_gemm_mfma, dim3(288, 9), dim3(256), 0, stream,
                       ws16 + X16H, ws16 + WTH, b_qkv, ws16);
    hipLaunchKernelGGL(k_attn_fused_mfma, dim3(3072), dim3(576), 0, stream,
                       ws16, mask, table, pidx, ws16 + AOH);
    hipLaunchKernelGGL(k_out_gemm_mfma, dim3(288, 3), dim3(256), 0, stream,
                       ws16 + AOH, ws16 + WOTH, b_out, out);
}